// Round 10
// baseline (481.279 us; speedup 1.0000x reference)
//
#include <hip/hip_runtime.h>
#include <math.h>

#define D 64

typedef __attribute__((ext_vector_type(8))) short bf16x8;
typedef __attribute__((ext_vector_type(4))) float f32x4;

static __device__ __forceinline__ unsigned short f2bf(float f) {
    unsigned int u = __float_as_uint(f);
    unsigned int r = (u + 0x7FFFu + ((u >> 16) & 1u)) >> 16;  // RNE
    return (unsigned short)r;
}
static __device__ __forceinline__ float bf2f(unsigned short h) {
    return __uint_as_float(((unsigned int)h) << 16);
}

#if defined(__has_builtin)
#if __has_builtin(__builtin_amdgcn_cvt_pk_bf16_f32)
#define HAVE_PK_BF16 1
#endif
#endif

static __device__ __forceinline__ unsigned int pk2bf(float a, float b) {
#ifdef HAVE_PK_BF16
    auto v = __builtin_amdgcn_cvt_pk_bf16_f32(a, b);   // low=a, high=b
    return *(unsigned int*)&v;
#else
    return (unsigned int)f2bf(a) | ((unsigned int)f2bf(b) << 16);
#endif
}

// tanh(x) = 1 - 2/(e^{2x}+1); inf-safe at extremes (no clamp needed)
static __device__ __forceinline__ float fast_tanh(float x) {
    float e = __expf(2.f * x);
    float r = __builtin_amdgcn_rcpf(e + 1.f);
    return 1.f - 2.f * r;
}

typedef __attribute__((address_space(1))) const unsigned int as1_uint;
typedef __attribute__((address_space(3))) unsigned int as3_uint;
static __device__ __forceinline__ void dma16(const void* g, void* l) {
    // async global->LDS, 16B/lane; LDS dest = uniform base + lane*16
    __builtin_amdgcn_global_load_lds((as1_uint*)g, (as3_uint*)l, 16, 0, 0);
}

// ---------------- pre-split W into MFMA B-fragment-ordered hi/lo bf16 arrays.
// B1 (GEMM1, P=feat@W):   element W[r][d=kb*32+q*8+j][o=c*16+m]
// B2 (GEMM2, V=u@W^T):    element W[r][d=c*16+m][o=kb*32+q*8+j]
// layout: [r][c][kb][lane=q*16+m][j]  -> chunk (r, c*2+kb) = 64 lanes x 16B
__global__ __launch_bounds__(256) void k_wsplit(const float* __restrict__ W,
                                                unsigned short* __restrict__ B1h,
                                                unsigned short* __restrict__ B1l,
                                                unsigned short* __restrict__ B2h,
                                                unsigned short* __restrict__ B2l,
                                                int R) {
    int idx = blockIdx.x * 256 + threadIdx.x;
    int per_g = R * 512;
    if (idx >= 2 * per_g) return;
    int g = idx / per_g;
    int rest = idx % per_g;
    int r = rest >> 9;
    int rest2 = rest & 511;
    int c = rest2 >> 7;
    int kb = (rest2 >> 6) & 1;
    int lane = rest2 & 63;
    int m = lane & 15, q = lane >> 4;
    bf16x8 hv, lv;
    #pragma unroll
    for (int j = 0; j < 8; ++j) {
        float v;
        if (g == 0) v = W[(size_t)r * 4096 + (kb * 32 + q * 8 + j) * 64 + (c * 16 + m)];
        else        v = W[(size_t)r * 4096 + (c * 16 + m) * 64 + (kb * 32 + q * 8 + j)];
        unsigned short h = f2bf(v);
        hv[j] = (short)h;
        lv[j] = (short)f2bf(v - bf2f(h));
    }
    size_t off = ((((size_t)r * 4 + c) * 2 + kb) * 64 + lane) * 8;
    unsigned short* ph = (g == 0) ? B1h : B2h;
    unsigned short* pl = (g == 0) ? B1l : B2l;
    *(bf16x8*)&ph[off] = hv;
    *(bf16x8*)&pl[off] = lv;
}

// ---------------- pre-split W1/W2 (for k_final): out = x @ Wk^T.
__global__ __launch_bounds__(256) void k_wsplit2(const float* __restrict__ W1,
                                                 const float* __restrict__ W2,
                                                 unsigned short* __restrict__ F1h,
                                                 unsigned short* __restrict__ F1l,
                                                 unsigned short* __restrict__ F2h,
                                                 unsigned short* __restrict__ F2l) {
    int idx = blockIdx.x * 256 + threadIdx.x;
    if (idx >= 1024) return;
    int g = idx >> 9;
    int rest2 = idx & 511;
    int c = rest2 >> 7;
    int kb = (rest2 >> 6) & 1;
    int lane = rest2 & 63;
    int m = lane & 15, q = lane >> 4;
    const float* W = g ? W2 : W1;
    bf16x8 hv, lv;
    #pragma unroll
    for (int j = 0; j < 8; ++j) {
        float v = W[(c * 16 + m) * 64 + kb * 32 + q * 8 + j];
        unsigned short h = f2bf(v);
        hv[j] = (short)h;
        lv[j] = (short)f2bf(v - bf2f(h));
    }
    size_t off = (((size_t)c * 2 + kb) * 64 + lane) * 8;
    unsigned short* ph = g ? F2h : F1h;
    unsigned short* pl = g ? F2l : F1l;
    *(bf16x8*)&ph[off] = hv;
    *(bf16x8*)&pl[off] = lv;
}

// ---------------- fused proj+V: phase-split ping-pong staging.
// GEMM1 (both s) reads chunks 0-15; GEMM2 reads 16-31. Each half is DMA-restaged
// immediately after its last reader, so the DMA has a full compute phase to land
// before the vmcnt drain at the next barrier. 40KB LDS -> 4 blocks/CU.
__global__ __launch_bounds__(256, 4) void k_projv(const float* __restrict__ feat,
                                                  const unsigned short* __restrict__ B1h,
                                                  const unsigned short* __restrict__ B1l,
                                                  const unsigned short* __restrict__ B2h,
                                                  const unsigned short* __restrict__ B2l,
                                                  const float* __restrict__ emb,
                                                  unsigned short* __restrict__ V,
                                                  int N, int R) {
    const int n0 = blockIdx.x * 128;
    __shared__ __align__(16) unsigned short Bbuf[32][512];   // 32 KB
    __shared__ __align__(16) unsigned short Us[4][1024];     // 8 KB (2KB/wave, per-s)
    const int t = threadIdx.x;
    const int lane = t & 63, w = t >> 6;
    const int m = lane & 15, q = lane >> 4;

    // ---- A-frags direct from global, split hi/lo in-register
    bf16x8 ah[2][2], al[2][2];
    #pragma unroll
    for (int s = 0; s < 2; ++s) {
        int n = n0 + w * 32 + s * 16 + m;
        const float* rowp = feat + (size_t)n * D;
        #pragma unroll
        for (int kb = 0; kb < 2; ++kb) {
            int d0 = kb * 32 + q * 8;
            float4 v0 = make_float4(0.f, 0.f, 0.f, 0.f), v1 = v0;
            if (n < N) { v0 = *(const float4*)(rowp + d0); v1 = *(const float4*)(rowp + d0 + 4); }
            float vals[8] = {v0.x, v0.y, v0.z, v0.w, v1.x, v1.y, v1.z, v1.w};
            bf16x8 hv, lv;
            #pragma unroll
            for (int j = 0; j < 8; ++j) {
                unsigned short h = f2bf(vals[j]);
                hv[j] = (short)h;
                lv[j] = (short)f2bf(vals[j] - bf2f(h));
            }
            ah[s][kb] = hv; al[s][kb] = lv;
        }
    }

    // stage half of Bbuf for relation r: half 0 = chunks 0-15 (B1h,B1l),
    // half 1 = chunks 16-31 (B2h,B2l). Wave w stages 4 chunks.
    auto stageH = [&](int r, int half) {
        #pragma unroll
        for (int i = 0; i < 4; ++i) {
            int g = half * 16 + w * 4 + i;
            int a = g >> 3;
            const unsigned short* arr = (a == 0) ? B1h : (a == 1) ? B1l : (a == 2) ? B2h : B2l;
            dma16(arr + (size_t)r * 4096 + (size_t)(g & 7) * 512 + lane * 8, &Bbuf[g][0]);
        }
    };

    stageH(0, 0);
    stageH(0, 1);
    __syncthreads();

    for (int r = 0; r < R; ++r) {
        float em[4];
        #pragma unroll
        for (int c = 0; c < 4; ++c) em[c] = emb[r * 64 + c * 16 + m];

        // ---------- GEMM1 (both s): P = feat @ W_r (3-term split), chunks 0-15
        f32x4 acc[4][2];
        #pragma unroll
        for (int c = 0; c < 4; ++c)
            #pragma unroll
            for (int s = 0; s < 2; ++s) acc[c][s] = (f32x4){0.f, 0.f, 0.f, 0.f};
        #pragma unroll
        for (int c = 0; c < 4; ++c) {
            bf16x8 bh[2], bl[2];
            #pragma unroll
            for (int kb = 0; kb < 2; ++kb) {
                bh[kb] = *(const bf16x8*)&Bbuf[c * 2 + kb][lane * 8];
                bl[kb] = *(const bf16x8*)&Bbuf[8 + c * 2 + kb][lane * 8];
            }
            #pragma unroll
            for (int kb = 0; kb < 2; ++kb)
                #pragma unroll
                for (int s = 0; s < 2; ++s) {
                    acc[c][s] = __builtin_amdgcn_mfma_f32_16x16x32_bf16(ah[s][kb], bh[kb], acc[c][s], 0, 0, 0);
                    acc[c][s] = __builtin_amdgcn_mfma_f32_16x16x32_bf16(al[s][kb], bh[kb], acc[c][s], 0, 0, 0);
                    acc[c][s] = __builtin_amdgcn_mfma_f32_16x16x32_bf16(ah[s][kb], bl[kb], acc[c][s], 0, 0, 0);
                }
        }

        __syncthreads();                 // all waves done reading chunks 0-15
        if (r + 1 < R) stageH(r + 1, 0); // restage half0; lands during phase2

        // ---------- phase2 per s: tanh -> Us -> GEMM2 -> store (chunks 16-31)
        #pragma unroll
        for (int s = 0; s < 2; ++s) {
            #pragma unroll
            for (int c = 0; c < 4; ++c) {
                int o = c * 16 + m;
                int kb2 = o >> 5;
                int q2 = (o >> 3) & 3;
                int j = o & 7;
                int Fb = kb2 * 64 + q2 * 16 + q * 4;
                #pragma unroll
                for (int i = 0; i < 4; i += 2) {
                    float t0 = fast_tanh(acc[c][s][i] + em[c]);
                    float t1 = fast_tanh(acc[c][s][i + 1] + em[c]);
                    unsigned int pk = pk2bf(t0, t1);
                    Us[w][((Fb + i) ^ q2) * 8 + j]     = (unsigned short)(pk & 0xFFFF);
                    Us[w][((Fb + i + 1) ^ q2) * 8 + j] = (unsigned short)(pk >> 16);
                }
            }

            bf16x8 ua[2];
            #pragma unroll
            for (int kb = 0; kb < 2; ++kb) {
                int F = kb * 64 + lane;
                ua[kb] = *(const bf16x8*)&Us[w][(F ^ (lane >> 4)) * 8];
            }
            f32x4 acc2[4];
            #pragma unroll
            for (int c = 0; c < 4; ++c) acc2[c] = (f32x4){0.f, 0.f, 0.f, 0.f};
            #pragma unroll
            for (int c = 0; c < 4; ++c) {
                bf16x8 bh[2], bl[2];
                #pragma unroll
                for (int kb = 0; kb < 2; ++kb) {
                    bh[kb] = *(const bf16x8*)&Bbuf[16 + c * 2 + kb][lane * 8];
                    bl[kb] = *(const bf16x8*)&Bbuf[24 + c * 2 + kb][lane * 8];
                }
                #pragma unroll
                for (int kb = 0; kb < 2; ++kb) {
                    acc2[c] = __builtin_amdgcn_mfma_f32_16x16x32_bf16(ua[kb], bh[kb], acc2[c], 0, 0, 0);
                    acc2[c] = __builtin_amdgcn_mfma_f32_16x16x32_bf16(ua[kb], bl[kb], acc2[c], 0, 0, 0);
                }
            }

            #pragma unroll
            for (int i = 0; i < 4; ++i) {
                int n = n0 + w * 32 + s * 16 + q * 4 + i;
                if (n < N) {
                    uint2 pv;
                    pv.x = pk2bf(acc2[0][i], acc2[1][i]);
                    pv.y = pk2bf(acc2[2][i], acc2[3][i]);
                    *(uint2*)&V[((size_t)n * R + r) * 64 + m * 4] = pv;
                }
            }
        }

        __syncthreads();                 // all waves done reading chunks 16-31
        if (r + 1 < R) stageH(r + 1, 1); // restage half1; lands during next GEMM1
    }
}

// ---------------- histogram of dst
__global__ __launch_bounds__(256) void k_hist(const int* __restrict__ dst, int* __restrict__ deg, int E) {
    int e = blockIdx.x * 256 + threadIdx.x;
    if (e < E) atomicAdd(&deg[dst[e]], 1);
}

// ---------------- scan step 1
__global__ __launch_bounds__(1024) void k_scan1(const int* __restrict__ deg, int* __restrict__ tscan,
                                                int* __restrict__ bsum, int N) {
    __shared__ int s[1024];
    const int t = threadIdx.x;
    const int i = blockIdx.x * 1024 + t;
    int v = (i < N) ? deg[i] : 0;
    s[t] = v;
    __syncthreads();
    for (int off = 1; off < 1024; off <<= 1) {
        int tmp = (t >= off) ? s[t - off] : 0;
        __syncthreads();
        s[t] += tmp;
        __syncthreads();
    }
    if (i < N) tscan[i] = s[t];
    if (t == 1023) bsum[blockIdx.x] = s[1023];
}

// ---------------- scan step 2
__global__ __launch_bounds__(1024) void k_scan2(const int* __restrict__ bsum, int* __restrict__ bofs, int NB) {
    __shared__ int s[1024];
    const int t = threadIdx.x;
    int carry = 0;
    for (int b0 = 0; b0 < NB; b0 += 1024) {
        int i = b0 + t;
        int v = (i < NB) ? bsum[i] : 0;
        s[t] = v;
        __syncthreads();
        for (int off = 1; off < 1024; off <<= 1) {
            int tmp = (t >= off) ? s[t - off] : 0;
            __syncthreads();
            s[t] += tmp;
            __syncthreads();
        }
        if (i < NB) bofs[i] = carry + s[t] - v;
        int tot = s[1023];
        __syncthreads();
        carry += tot;
    }
}

// ---------------- scan step 3
__global__ __launch_bounds__(256) void k_scan3(const int* __restrict__ tscan, const int* __restrict__ bofs,
                                               int* __restrict__ offsets, int* __restrict__ cursor, int N) {
    int i = blockIdx.x * 256 + threadIdx.x;
    if (i <= N) {
        int v = (i == 0) ? 0 : (tscan[i - 1] + bofs[(i - 1) >> 10]);
        offsets[i] = v;
        if (i < N) cursor[i] = v;
    }
}

// ---------------- scatter edges into dst-sorted order
__global__ __launch_bounds__(256) void k_scatter(const int* __restrict__ src, const int* __restrict__ dst,
                                                 const int* __restrict__ etype, int* __restrict__ cursor,
                                                 int* __restrict__ spack, int E) {
    int e = blockIdx.x * 256 + threadIdx.x;
    if (e < E) {
        int d = dst[e];
        int p = atomicAdd(&cursor[d], 1);
        spack[p] = src[e] | (etype[e] << 20);
    }
}

// ---------------- fused att + softmax + aggregation: 4 edges per wave-iteration.
__global__ __launch_bounds__(256) void k_fused2(const unsigned short* __restrict__ V,
                                                const float* __restrict__ feat,
                                                const int* __restrict__ offsets,
                                                const int* __restrict__ spack,
                                                float* __restrict__ h_nb,
                                                int N, int R) {
    const int lane = threadIdx.x & 63;
    const int wav  = threadIdx.x >> 6;
    const int g    = lane >> 4;
    const int k    = lane & 15;
    const int n = blockIdx.x * 4 + wav;
    __shared__ float vlds[4][1024];
    if (n >= N) return;

    const unsigned int* v32 = (const unsigned int*)(V + (size_t)n * R * D);
    #pragma unroll
    for (int j = 0; j < 8; ++j) {
        int uidx = j * 64 + lane;
        unsigned int u = v32[uidx];
        int r  = uidx >> 5;
        int k2 = uidx & 31;
        int mm = k2 >> 1;
        int cc = (k2 & 1) * 2;
        int o  = cc * 16 + mm;
        vlds[wav][r * 64 + o]      = bf2f((unsigned short)(u & 0xFFFF));
        vlds[wav][r * 64 + o + 16] = bf2f((unsigned short)(u >> 16));
    }

    const int beg = offsets[n], end = offsets[n + 1];
    float m = -INFINITY, l = 0.f;
    float4 acc = make_float4(0.f, 0.f, 0.f, 0.f);

    if (beg < end) {
        int e = beg + g;
        bool ok = e < end;
        int pk = spack[ok ? e : (end - 1)];
        float4 f = *(const float4*)&feat[(size_t)(pk & 0xFFFFF) * D + k * 4];

        for (int i = beg; i < end; i += 4) {
            const int   et  = pk >> 20;
            const float4 fc = f;
            const bool  okc = ok;
            int e2 = i + 4 + g;
            ok = e2 < end;
            pk = spack[ok ? e2 : (end - 1)];
            f = *(const float4*)&feat[(size_t)(pk & 0xFFFFF) * D + k * 4];

            float4 v = *(const float4*)&vlds[wav][et * 64 + k * 4];
            float p = fc.x * v.x + fc.y * v.y + fc.z * v.z + fc.w * v.w;
            p += __shfl_xor(p, 1, 64);
            p += __shfl_xor(p, 2, 64);
            p += __shfl_xor(p, 4, 64);
            p += __shfl_xor(p, 8, 64);
            p = okc ? p : -INFINITY;
            float tmx = fmaxf(p, __shfl_xor(p, 16, 64));
            float nm4 = fmaxf(tmx, __shfl_xor(tmx, 32, 64));
            float nm  = fmaxf(m, nm4);
            float scale = __expf(m - nm);
            float wg    = __expf(p - nm);
            float sw = wg + __shfl_xor(wg, 16, 64);
            sw += __shfl_xor(sw, 32, 64);
            l = l * scale + sw;
            acc.x = acc.x * scale + wg * fc.x;
            acc.y = acc.y * scale + wg * fc.y;
            acc.z = acc.z * scale + wg * fc.z;
            acc.w = acc.w * scale + wg * fc.w;
            m = nm;
        }
        acc.x += __shfl_xor(acc.x, 16, 64);
        acc.y += __shfl_xor(acc.y, 16, 64);
        acc.z += __shfl_xor(acc.z, 16, 64);
        acc.w += __shfl_xor(acc.w, 16, 64);
        acc.x += __shfl_xor(acc.x, 32, 64);
        acc.y += __shfl_xor(acc.y, 32, 64);
        acc.z += __shfl_xor(acc.z, 32, 64);
        acc.w += __shfl_xor(acc.w, 32, 64);
        float inv = 1.f / l;
        acc.x *= inv; acc.y *= inv; acc.z *= inv; acc.w *= inv;
    }
    if (lane < 16)
        *(float4*)&h_nb[(size_t)n * D + k * 4] = acc;
}

// ---------------- final via MFMA: out = lrelu((f+h)@W1^T) + lrelu((f*h)@W2^T)
__global__ __launch_bounds__(256, 2) void k_final(const float* __restrict__ feat,
                                                  const float* __restrict__ h_nb,
                                                  const unsigned short* __restrict__ F1h,
                                                  const unsigned short* __restrict__ F1l,
                                                  const unsigned short* __restrict__ F2h,
                                                  const unsigned short* __restrict__ F2l,
                                                  float* __restrict__ out, int N) {
    const int n0 = blockIdx.x * 128;
    __shared__ __align__(16) unsigned short Wlds[4][4096];
    const int t = threadIdx.x;
    const int lane = t & 63, w = t >> 6;
    const int m = lane & 15, q = lane >> 4;

    const unsigned short* warr = (w == 0) ? F1h : (w == 1) ? F1l : (w == 2) ? F2h : F2l;
    #pragma unroll
    for (int i = 0; i < 8; ++i)
        dma16(warr + i * 512 + lane * 8, &Wlds[w][i * 512]);

    bf16x8 sh[2][2], sl[2][2], ph[2][2], pl[2][2];
    #pragma unroll
    for (int s = 0; s < 2; ++s) {
        int n = n0 + w * 32 + s * 16 + m;
        const float* fp = feat + (size_t)n * D;
        const float* hp = h_nb + (size_t)n * D;
        #pragma unroll
        for (int kb = 0; kb < 2; ++kb) {
            int d0 = kb * 32 + q * 8;
            float4 f0 = make_float4(0.f, 0.f, 0.f, 0.f), f1 = f0, h0 = f0, h1 = f0;
            if (n < N) {
                f0 = *(const float4*)(fp + d0); f1 = *(const float4*)(fp + d0 + 4);
                h0 = *(const float4*)(hp + d0); h1 = *(const float4*)(hp + d0 + 4);
            }
            float fv[8] = {f0.x, f0.y, f0.z, f0.w, f1.x, f1.y, f1.z, f1.w};
            float hv[8] = {h0.x, h0.y, h0.z, h0.w, h1.x, h1.y, h1.z, h1.w};
            bf16x8 a, b, c2, d2;
            #pragma unroll
            for (int j = 0; j < 8; ++j) {
                float xs = fv[j] + hv[j];
                float xp = fv[j] * hv[j];
                unsigned short hs = f2bf(xs);
                unsigned short hp2 = f2bf(xp);
                a[j]  = (short)hs;
                b[j]  = (short)f2bf(xs - bf2f(hs));
                c2[j] = (short)hp2;
                d2[j] = (short)f2bf(xp - bf2f(hp2));
            }
            sh[s][kb] = a; sl[s][kb] = b; ph[s][kb] = c2; pl[s][kb] = d2;
        }
    }
    __syncthreads();

    f32x4 a1[4][2], a2[4][2];
    #pragma unroll
    for (int c = 0; c < 4; ++c)
        #pragma unroll
        for (int s = 0; s < 2; ++s) {
            a1[c][s] = (f32x4){0.f, 0.f, 0.f, 0.f};
            a2[c][s] = (f32x4){0.f, 0.f, 0.f, 0.f};
        }
    #pragma unroll
    for (int c = 0; c < 4; ++c) {
        bf16x8 b1h[2], b1l[2], b2h[2], b2l[2];
        #pragma unroll
        for (int kb = 0; kb < 2; ++kb) {
            int o = (c * 2 + kb) * 512 + lane * 8;
            b1h[kb] = *(const bf16x8*)&Wlds[0][o];
            b1l[kb] = *(const bf16x8*)&Wlds[1][o];
            b2h[kb] = *(const bf16x8*)&Wlds[2][o];
            b2l[kb] = *(const bf16x8*)&Wlds[3][o];
        }
        #pragma unroll
        for (int kb = 0; kb < 2; ++kb)
            #pragma unroll
            for (int s = 0; s < 2; ++s) {
                a1[c][s] = __builtin_amdgcn_mfma_f32_16x16x32_bf16(sh[s][kb], b1h[kb], a1[c][s], 0, 0, 0);
                a1[c][s] = __builtin_amdgcn_mfma_f32_16x16x32_bf16(sl[s][kb], b1h[kb], a1[c][s], 0, 0, 0);
                a1[c][s] = __builtin_amdgcn_mfma_f32_16x16x32_bf16(sh[s][kb], b1l[kb], a1[c][s], 0, 0, 0);
                a2[c][s] = __builtin_amdgcn_mfma_f32_16x16x32_bf16(ph[s][kb], b2h[kb], a2[c][s], 0, 0, 0);
                a2[c][s] = __builtin_amdgcn_mfma_f32_16x16x32_bf16(pl[s][kb], b2h[kb], a2[c][s], 0, 0, 0);
                a2[c][s] = __builtin_amdgcn_mfma_f32_16x16x32_bf16(ph[s][kb], b2l[kb], a2[c][s], 0, 0, 0);
            }
    }

    #pragma unroll
    for (int s = 0; s < 2; ++s)
        #pragma unroll
        for (int i = 0; i < 4; ++i) {
            int n = n0 + w * 32 + s * 16 + q * 4 + i;
            if (n < N) {
                #pragma unroll
                for (int c = 0; c < 4; ++c) {
                    float o1 = a1[c][s][i];
                    float o2 = a2[c][s][i];
                    o1 = (o1 > 0.f) ? o1 : 0.01f * o1;
                    o2 = (o2 > 0.f) ? o2 : 0.01f * o2;
                    out[(size_t)n * D + c * 16 + m] = o1 + o2;
                }
            }
        }
}

extern "C" void kernel_launch(void* const* d_in, const int* in_sizes, int n_in,
                              void* d_out, int out_size, void* d_ws, size_t ws_size,
                              hipStream_t stream) {
    const float* feat  = (const float*)d_in[0];
    const float* relW  = (const float*)d_in[1];
    const float* relE  = (const float*)d_in[2];
    const float* W1    = (const float*)d_in[3];
    const float* W2    = (const float*)d_in[4];
    const int*   src   = (const int*)d_in[5];
    const int*   dst   = (const int*)d_in[6];
    const int*   etype = (const int*)d_in[7];
    float* out = (float*)d_out;

    const int N = in_sizes[0] / D;
    const int R = in_sizes[2] / D;
    const int E = in_sizes[5];

    char* w = (char*)d_ws;
    size_t off = 0;
    auto alloc = [&](size_t bytes) -> void* {
        void* p = w + off;
        off = (off + bytes + 255) & ~(size_t)255;
        return p;
    };
    unsigned short* varr = (unsigned short*)alloc((size_t)N * R * D * sizeof(unsigned short));
    float* h_nb   = (float*)alloc((size_t)N * D * sizeof(float));
    int* offsets  = (int*)alloc((size_t)(N + 1) * sizeof(int));
    int* tscan    = (int*)alloc((size_t)N * sizeof(int));
    int* cursor   = (int*)alloc((size_t)N * sizeof(int));
    int* deg      = (int*)alloc((size_t)N * sizeof(int));
    int* bsum     = (int*)alloc(2048 * sizeof(int));
    int* bofs     = (int*)alloc(2048 * sizeof(int));
    int* spack    = (int*)alloc((size_t)E * sizeof(int));
    size_t wfrag = (size_t)R * 4 * 2 * 64 * 8;
    unsigned short* B1h = (unsigned short*)alloc(wfrag * sizeof(unsigned short));
    unsigned short* B1l = (unsigned short*)alloc(wfrag * sizeof(unsigned short));
    unsigned short* B2h = (unsigned short*)alloc(wfrag * sizeof(unsigned short));
    unsigned short* B2l = (unsigned short*)alloc(wfrag * sizeof(unsigned short));
    unsigned short* F1h = (unsigned short*)alloc(4096 * sizeof(unsigned short));
    unsigned short* F1l = (unsigned short*)alloc(4096 * sizeof(unsigned short));
    unsigned short* F2h = (unsigned short*)alloc(4096 * sizeof(unsigned short));
    unsigned short* F2l = (unsigned short*)alloc(4096 * sizeof(unsigned short));
    (void)ws_size; (void)n_in; (void)out_size;

    const int NB = (N + 1023) / 1024;

    k_wsplit<<<(2 * R * 512 + 255) / 256, 256, 0, stream>>>(relW, B1h, B1l, B2h, B2l, R);
    k_wsplit2<<<4, 256, 0, stream>>>(W1, W2, F1h, F1l, F2h, F2l);
    hipMemsetAsync(deg, 0, (size_t)N * sizeof(int), stream);
    k_hist<<<(E + 255) / 256, 256, 0, stream>>>(dst, deg, E);
    k_scan1<<<NB, 1024, 0, stream>>>(deg, tscan, bsum, N);
    k_scan2<<<1, 1024, 0, stream>>>(bsum, bofs, NB);
    k_scan3<<<(N + 1 + 255) / 256, 256, 0, stream>>>(tscan, bofs, offsets, cursor, N);
    k_scatter<<<(E + 255) / 256, 256, 0, stream>>>(src, dst, etype, cursor, spack, E);
    k_projv<<<(N + 127) / 128, 256, 0, stream>>>(feat, B1h, B1l, B2h, B2l, relE, varr, N, R);
    k_fused2<<<(N + 3) / 4, 256, 0, stream>>>(varr, feat, offsets, spack, h_nb, N, R);
    k_final<<<(N + 127) / 128, 256, 0, stream>>>(feat, h_nb, F1h, F1l, F2h, F2l, out, N);
}